// Round 1
// baseline (1149.441 us; speedup 1.0000x reference)
//
#include <hip/hip_runtime.h>

// ---------- types ----------
typedef __bf16 bf16x8 __attribute__((ext_vector_type(8)));
typedef float f32x4 __attribute__((ext_vector_type(4)));
typedef unsigned short us8 __attribute__((ext_vector_type(8)));
typedef unsigned short us2 __attribute__((ext_vector_type(2)));

#define SCALE_Q 0.17677669529663687f  // 32^-0.5

__device__ __forceinline__ unsigned short f2b(float f) {
    union { float f; unsigned u; } v; v.f = f;
    unsigned r = v.u + 0x7FFFu + ((v.u >> 16) & 1u);   // RNE
    return (unsigned short)(r >> 16);
}
__device__ __forceinline__ float b2f(unsigned short h) {
    union { unsigned u; float f; } v; v.u = ((unsigned)h) << 16;
    return v.f;
}
__device__ __forceinline__ f32x4 mfma16(us8 a, us8 b, f32x4 c) {
    return __builtin_amdgcn_mfma_f32_16x16x32_bf16(
        __builtin_bit_cast(bf16x8, a), __builtin_bit_cast(bf16x8, b), c, 0, 0, 0);
}

// ---------- weight transpose + bf16 convert:  dst[c][r] = src[r][c] ----------
__global__ void k_transpose(const float* __restrict__ src, unsigned short* __restrict__ dst,
                            int R, int C) {
    int idx = blockIdx.x * 256 + threadIdx.x;
    if (idx >= R * C) return;
    int r = idx / C, c = idx - r * C;
    dst[c * R + r] = f2b(src[idx]);
}

// ---------- LayerNorm (one wave per token). GATHER: write to rolled+windowed row ----------
template<bool GATHER>
__global__ __launch_bounds__(256) void k_ln(const float* __restrict__ xin,
        const float* __restrict__ sc, const float* __restrict__ bi,
        unsigned short* __restrict__ yout) {
    int wave = threadIdx.x >> 6, lane = threadIdx.x & 63;
    int t = blockIdx.x * 4 + wave;                 // token 0..262143 (standard layout)
    const float* row = xin + (size_t)t * 128;
    float2 v = *(const float2*)(row + lane * 2);
    float sum = v.x + v.y;
    float sq = v.x * v.x + v.y * v.y;
    #pragma unroll
    for (int m = 1; m < 64; m <<= 1) {
        sum += __shfl_xor(sum, m);
        sq  += __shfl_xor(sq, m);
    }
    float mu = sum * 0.0078125f;
    float var = sq * 0.0078125f - mu * mu;
    float rstd = rsqrtf(var + 1e-6f);
    int c0 = lane * 2;
    float y0 = (v.x - mu) * rstd * sc[c0] + bi[c0];
    float y1 = (v.y - mu) * rstd * sc[c0 + 1] + bi[c0 + 1];
    int drow;
    if (GATHER) {
        // rolled coord: rolled[hr] = x[(hr+2)%64]  =>  hr = (hh-2) mod 64
        int b = t >> 12, hh = (t >> 6) & 63, ww = t & 63;
        int hr = (hh - 2) & 63, wr = (ww - 2) & 63;
        int win = (b << 8) | ((hr >> 2) << 4) | (wr >> 2);
        drow = win * 16 + (((hr & 3) << 2) | (wr & 3));
    } else {
        drow = t;
    }
    us2 o; o[0] = f2b(y0); o[1] = f2b(y1);
    *(us2*)(yout + (size_t)drow * 128 + c0) = o;
}

// ---------- generic MFMA GEMM: wave computes 16x64 tile;  C = A(MxK) * Bt(NxK)^T ----------
// EPI 0: QKV (bias, scale q, scatter to [win][s][h][tok][hd] bf16)
// EPI 1: proj (bias + residual x, window-reverse+roll scatter, fp32 out)
// EPI 2: FC1 (bias + gelu, bf16 out, local rows)
// EPI 3: FC2 (bias + residual, fp32 in-place out)
template<int EPI, int KDIM>
__global__ __launch_bounds__(256) void k_gemm(
        const unsigned short* __restrict__ A,
        const unsigned short* __restrict__ Bt,
        const float* __restrict__ bias,
        const float* resid,          // no __restrict__: may alias outF (FC2)
        float* outF,
        unsigned short* __restrict__ outB,
        int aOff, int oOff) {
    int wave = threadIdx.x >> 6, lane = threadIdx.x & 63;
    int m16 = lane & 15, g = lane >> 4;
    int r0 = blockIdx.x * 64 + wave * 16;          // local row base
    int c0 = blockIdx.y * 64;                      // col base
    f32x4 acc[4] = {{0.f,0.f,0.f,0.f},{0.f,0.f,0.f,0.f},{0.f,0.f,0.f,0.f},{0.f,0.f,0.f,0.f}};
    const unsigned short* Ap = A + (size_t)(aOff + r0 + m16) * KDIM + g * 8;
    const unsigned short* Bp = Bt + (size_t)(c0 + m16) * KDIM + g * 8;
    #pragma unroll
    for (int k0 = 0; k0 < KDIM; k0 += 32) {
        us8 a = *(const us8*)(Ap + k0);
        #pragma unroll
        for (int nt = 0; nt < 4; ++nt) {
            us8 b = *(const us8*)(Bp + (size_t)nt * 16 * KDIM + k0);
            acc[nt] = mfma16(a, b, acc[nt]);
        }
    }
    #pragma unroll
    for (int nt = 0; nt < 4; ++nt) {
        #pragma unroll
        for (int jj = 0; jj < 4; ++jj) {
            int r = r0 + g * 4 + jj;               // local row (C/D: row=(lane>>4)*4+reg)
            int c = c0 + nt * 16 + m16;            // col       (C/D: col=lane&15)
            float v = acc[nt][jj] + bias[c];
            if constexpr (EPI == 0) {
                if (c < 128) v *= SCALE_Q;
                int winw = r >> 4, tok = r & 15;
                int s = c >> 7, rem = c & 127;
                int hq = rem >> 5, hd = rem & 31;
                outB[((((size_t)winw * 3 + s) * 4 + hq) * 16 + tok) * 32 + hd] = f2b(v);
            } else if constexpr (EPI == 1) {
                int winw = r >> 4, tok = r & 15;
                int b = winw >> 8, wm = winw & 255;
                int hh = (((wm >> 4) << 2) + (tok >> 2) + 2) & 63;   // un-roll (+2)
                int ww = (((wm & 15) << 2) + (tok & 3) + 2) & 63;
                size_t t = ((size_t)b << 12) | (unsigned)(hh << 6) | (unsigned)ww;
                outF[t * 128 + c] = v + resid[t * 128 + c];
            } else if constexpr (EPI == 2) {
                // gelu(tanh approx) = v * sigmoid(2*0.7978845608*(v + 0.044715 v^3))
                float z = v + 0.044715f * v * v * v;
                float sg = 1.f / (1.f + __expf(-1.5957691216057308f * z));
                outB[(size_t)r * 512 + c] = f2b(v * sg);
            } else {
                size_t gr = (size_t)(r + oOff);
                outF[gr * 128 + c] = v + resid[gr * 128 + c];
            }
        }
    }
}

// ---------- fused window attention: one wave per window, lane = head*16 + query ----------
__global__ __launch_bounds__(256) void k_attn(const unsigned short* __restrict__ qkv,
        const float* __restrict__ relb, unsigned short* __restrict__ outp) {
    __shared__ unsigned short sm[4][6144];   // 4 windows * (3*4*16*32) bf16 = 48KB
    __shared__ float sbias[196];             // rel_bias (49,4)
    int wave = threadIdx.x >> 6, lane = threadIdx.x & 63;
    int win = blockIdx.x * 4 + wave;
    {
        const uint4* src = (const uint4*)(qkv + (size_t)win * 6144);
        uint4* dst = (uint4*)(&sm[wave][0]);
        #pragma unroll
        for (int it = 0; it < 12; ++it) dst[it * 64 + lane] = src[it * 64 + lane];
    }
    if (threadIdx.x < 196) sbias[threadIdx.x] = relb[threadIdx.x];
    __syncthreads();
    int h = lane >> 4, n = lane & 15;
    // q (already scaled in QKV epilogue)
    float qv[32];
    {
        const unsigned short* qp = &sm[wave][(h * 16 + n) * 32];
        #pragma unroll
        for (int d8 = 0; d8 < 4; ++d8) {
            us8 u = *(const us8*)(qp + d8 * 8);
            #pragma unroll
            for (int jj = 0; jj < 8; ++jj) qv[d8 * 8 + jj] = b2f(u[jj]);
        }
    }
    int wm = win & 255, wh = wm >> 4, wwn = wm & 15;
    int ti = n >> 2, tj = n & 3;
    int hh = wh * 4 + ti, ww = wwn * 4 + tj;           // rolled-frame coords (mask frame)
    int myid = (hh < 60 ? 0 : (hh < 62 ? 3 : 6)) + (ww < 60 ? 0 : (ww < 62 ? 1 : 2));
    float p[16];
    const unsigned short* kbase = &sm[wave][(4 + h) * 512];
    #pragma unroll
    for (int kp = 0; kp < 16; ++kp) {
        const unsigned short* kr = kbase + kp * 32;
        float acc = 0.f;
        #pragma unroll
        for (int d8 = 0; d8 < 4; ++d8) {
            us8 u = *(const us8*)(kr + d8 * 8);
            #pragma unroll
            for (int jj = 0; jj < 8; ++jj) acc += qv[d8 * 8 + jj] * b2f(u[jj]);
        }
        int pi = kp >> 2, pj = kp & 3;
        int ph = wh * 4 + pi, pw = wwn * 4 + pj;
        int pid = (ph < 60 ? 0 : (ph < 62 ? 3 : 6)) + (pw < 60 ? 0 : (pw < 62 ? 1 : 2));
        acc += sbias[((ti - pi + 3) * 7 + (tj - pj + 3)) * 4 + h];
        if (pid != myid) acc -= 100.f;
        p[kp] = acc;
    }
    // softmax applied twice (faithful to reference)
    #pragma unroll
    for (int rep = 0; rep < 2; ++rep) {
        float mx = p[0];
        #pragma unroll
        for (int kp = 1; kp < 16; ++kp) mx = fmaxf(mx, p[kp]);
        float s = 0.f;
        #pragma unroll
        for (int kp = 0; kp < 16; ++kp) { p[kp] = __expf(p[kp] - mx); s += p[kp]; }
        float inv = 1.f / s;
        #pragma unroll
        for (int kp = 0; kp < 16; ++kp) p[kp] *= inv;
    }
    float o[32];
    #pragma unroll
    for (int d = 0; d < 32; ++d) o[d] = 0.f;
    const unsigned short* vbase = &sm[wave][(8 + h) * 512];
    #pragma unroll
    for (int kp = 0; kp < 16; ++kp) {
        const unsigned short* vr = vbase + kp * 32;
        float w = p[kp];
        #pragma unroll
        for (int d8 = 0; d8 < 4; ++d8) {
            us8 u = *(const us8*)(vr + d8 * 8);
            #pragma unroll
            for (int jj = 0; jj < 8; ++jj) o[d8 * 8 + jj] += w * b2f(u[jj]);
        }
    }
    unsigned short* op = outp + (size_t)(win * 16 + n) * 128 + h * 32;
    #pragma unroll
    for (int d8 = 0; d8 < 4; ++d8) {
        us8 u;
        #pragma unroll
        for (int jj = 0; jj < 8; ++jj) u[jj] = f2b(o[d8 * 8 + jj]);
        *(us8*)(op + d8 * 8) = u;
    }
}

// ---------- launch ----------
extern "C" void kernel_launch(void* const* d_in, const int* in_sizes, int n_in,
                              void* d_out, int out_size, void* d_ws, size_t ws_size,
                              hipStream_t stream) {
    const float* x        = (const float*)d_in[0];
    const float* ln1_s    = (const float*)d_in[1];
    const float* ln1_b    = (const float*)d_in[2];
    const float* qkv_w    = (const float*)d_in[3];
    const float* qkv_b    = (const float*)d_in[4];
    const float* rel_bias = (const float*)d_in[5];
    const float* proj_w   = (const float*)d_in[6];
    const float* proj_b   = (const float*)d_in[7];
    const float* ln2_s    = (const float*)d_in[8];
    const float* ln2_b    = (const float*)d_in[9];
    const float* fc1_w    = (const float*)d_in[10];
    const float* fc1_b    = (const float*)d_in[11];
    const float* fc2_w    = (const float*)d_in[12];
    const float* fc2_b    = (const float*)d_in[13];
    float* out = (float*)d_out;
    char* ws = (char*)d_ws;

    // ws layout (total ~256.5 MB):
    unsigned short* qkv_wt  = (unsigned short*)(ws);             // 384x128 bf16
    unsigned short* proj_wt = (unsigned short*)(ws + 98304);     // 128x128
    unsigned short* fc1_wt  = (unsigned short*)(ws + 131072);    // 512x128
    unsigned short* fc2_wt  = (unsigned short*)(ws + 262144);    // 128x512
    unsigned short* ybuf    = (unsigned short*)(ws + 524288);                // 64MB  (M x 128 bf16, window rows)
    unsigned short* qkvbuf  = (unsigned short*)(ws + 524288 + 67108864);     // 192MB (M x 384 bf16, [win][s][h][tok][hd])
    unsigned short* attnout = ybuf;                                          // reuse (y dead after QKV)
    unsigned short* ln2buf  = qkvbuf;                                        // reuse (qkv dead after attn), 64MB
    unsigned short* hidden  = (unsigned short*)(ws + 524288 + 67108864 + 67108864); // 128MB chunk
    // x_mid lives in d_out (fp32, token-major)

    // weight prep
    k_transpose<<<192, 256, 0, stream>>>(qkv_w, qkv_wt, 128, 384);
    k_transpose<<<64,  256, 0, stream>>>(proj_w, proj_wt, 128, 128);
    k_transpose<<<256, 256, 0, stream>>>(fc1_w, fc1_wt, 128, 512);
    k_transpose<<<256, 256, 0, stream>>>(fc2_w, fc2_wt, 512, 128);

    // LN1 + roll + window partition -> ybuf (window rows)
    k_ln<true><<<65536, 256, 0, stream>>>(x, ln1_s, ln1_b, ybuf);
    // QKV GEMM (M=262144, K=128, N=384)
    k_gemm<0, 128><<<dim3(4096, 6), 256, 0, stream>>>(ybuf, qkv_wt, qkv_b, nullptr, nullptr, qkvbuf, 0, 0);
    // fused window attention
    k_attn<<<4096, 256, 0, stream>>>(qkvbuf, rel_bias, attnout);
    // proj GEMM + window reverse + roll + residual -> d_out (= x_mid)
    k_gemm<1, 128><<<dim3(4096, 2), 256, 0, stream>>>(attnout, proj_wt, proj_b, x, out, nullptr, 0, 0);
    // LN2 -> ln2buf (bf16, token-major)
    k_ln<false><<<65536, 256, 0, stream>>>(out, ln2_s, ln2_b, ln2buf);
    // MLP in 2 chunks of 131072 rows (hidden buffer reuse)
    for (int c = 0; c < 262144; c += 131072) {
        k_gemm<2, 128><<<dim3(2048, 8), 256, 0, stream>>>(ln2buf, fc1_wt, fc1_b, nullptr, nullptr, hidden, c, 0);
        k_gemm<3, 512><<<dim3(2048, 2), 256, 0, stream>>>(hidden, fc2_wt, fc2_b, out, out, nullptr, 0, c);
    }
}

// Round 2
// 456.132 us; speedup vs baseline: 2.5200x; 2.5200x over previous
//
#include <hip/hip_runtime.h>

typedef __bf16 bf16x8 __attribute__((ext_vector_type(8)));
typedef float f32x4 __attribute__((ext_vector_type(4)));
typedef unsigned short us8 __attribute__((ext_vector_type(8)));

#define SCALE_Q 0.17677669529663687f  // 32^-0.5

__device__ __forceinline__ unsigned short f2b(float f) {
    union { float f; unsigned u; } v; v.f = f;
    unsigned r = v.u + 0x7FFFu + ((v.u >> 16) & 1u);   // RNE
    return (unsigned short)(r >> 16);
}
__device__ __forceinline__ float b2f(unsigned short h) {
    union { unsigned u; float f; } v; v.u = ((unsigned)h) << 16;
    return v.f;
}
__device__ __forceinline__ f32x4 mfma16(us8 a, us8 b, f32x4 c) {
    return __builtin_amdgcn_mfma_f32_16x16x32_bf16(
        __builtin_bit_cast(bf16x8, a), __builtin_bit_cast(bf16x8, b), c, 0, 0, 0);
}
__device__ __forceinline__ us8 lds_ld8(const unsigned short* base, int byteoff) {
    return *(const us8*)((const char*)base + byteoff);
}
__device__ __forceinline__ void lds_st8(unsigned short* base, int byteoff, us8 v) {
    *(us8*)((char*)base + byteoff) = v;
}

// ---------- weight transpose + bf16 convert:  dst[c][r] = src[r][c] ----------
__global__ void k_transpose(const float* __restrict__ src, unsigned short* __restrict__ dst,
                            int R, int C) {
    int idx = blockIdx.x * 256 + threadIdx.x;
    if (idx >= R * C) return;
    int r = idx / C, c = idx - r * C;
    dst[c * R + r] = f2b(src[idx]);
}

// =====================================================================
// K1: LN1 + roll + window-partition + QKV + attention + proj + residual
// One wave per window (16 tokens). Per-wave LDS slice sQ[wave][6144]:
//   [0..2048)  : Q region; doubles as LN'd A-tile (phase A/B), then Q
//   [2048..4096): K region; doubles as attn-out tile for proj (phase D)
//   [4096..6144): V region
// =====================================================================
__global__ __launch_bounds__(256) void k_block1(
    const float* __restrict__ x,
    const float* __restrict__ ln1s, const float* __restrict__ ln1b,
    const unsigned short* __restrict__ qkvW, const float* __restrict__ qkvB,
    const float* __restrict__ relb,
    const unsigned short* __restrict__ projW, const float* __restrict__ projB,
    float* __restrict__ out)
{
    __shared__ unsigned short sQ[4][6144];
    __shared__ float sbias[196];
    const int tid = threadIdx.x;
    const int wave = tid >> 6, lane = tid & 63;
    const int g = lane >> 4, m16 = lane & 15;
    if (tid < 196) sbias[tid] = relb[tid];
    const int win = blockIdx.x * 4 + wave;
    const int bb = win >> 8, wh = (win >> 4) & 15, wn = win & 15;
    unsigned short* sW = &sQ[wave][0];

    // ---- phase A: LN1 + roll-gather -> sW as [16][128] bf16, XOR-swizzled ----
    float4 sc0 = *(const float4*)(ln1s + m16 * 8);
    float4 sc1 = *(const float4*)(ln1s + m16 * 8 + 4);
    float4 bi0 = *(const float4*)(ln1b + m16 * 8);
    float4 bi1 = *(const float4*)(ln1b + m16 * 8 + 4);
    #pragma unroll
    for (int it = 0; it < 4; ++it) {
        int tok = it * 4 + g;
        int ti = tok >> 2, tj = tok & 3;
        int hh = (wh * 4 + ti + 2) & 63, ww = (wn * 4 + tj + 2) & 63;
        const float* xr = x + ((((size_t)bb << 12) | (hh << 6) | ww) * 128) + m16 * 8;
        float4 v0 = *(const float4*)xr, v1 = *(const float4*)(xr + 4);
        float sum = v0.x + v0.y + v0.z + v0.w + v1.x + v1.y + v1.z + v1.w;
        float sq  = v0.x*v0.x + v0.y*v0.y + v0.z*v0.z + v0.w*v0.w
                  + v1.x*v1.x + v1.y*v1.y + v1.z*v1.z + v1.w*v1.w;
        #pragma unroll
        for (int m = 1; m < 16; m <<= 1) { sum += __shfl_xor(sum, m); sq += __shfl_xor(sq, m); }
        float mu = sum * 0.0078125f;
        float rstd = rsqrtf(sq * 0.0078125f - mu * mu + 1e-6f);
        us8 o;
        o[0] = f2b((v0.x - mu) * rstd * sc0.x + bi0.x);
        o[1] = f2b((v0.y - mu) * rstd * sc0.y + bi0.y);
        o[2] = f2b((v0.z - mu) * rstd * sc0.z + bi0.z);
        o[3] = f2b((v0.w - mu) * rstd * sc0.w + bi0.w);
        o[4] = f2b((v1.x - mu) * rstd * sc1.x + bi1.x);
        o[5] = f2b((v1.y - mu) * rstd * sc1.y + bi1.y);
        o[6] = f2b((v1.z - mu) * rstd * sc1.z + bi1.z);
        o[7] = f2b((v1.w - mu) * rstd * sc1.w + bi1.w);
        lds_st8(sW, (tok * 256) + ((m16 * 16) ^ ((tok & 7) << 4)), o);
    }
    __syncthreads();   // sbias visibility (phase work is wave-local)

    // ---- phase B: QKV GEMM (16 x 384), A-frags hoisted, B from L2 ----
    us8 a0 = lds_ld8(sW, (m16 * 256) + ((  0 + g * 16) ^ ((m16 & 7) << 4)));
    us8 a1 = lds_ld8(sW, (m16 * 256) + (( 64 + g * 16) ^ ((m16 & 7) << 4)));
    us8 a2 = lds_ld8(sW, (m16 * 256) + ((128 + g * 16) ^ ((m16 & 7) << 4)));
    us8 a3 = lds_ld8(sW, (m16 * 256) + ((192 + g * 16) ^ ((m16 & 7) << 4)));
    #pragma unroll
    for (int ct = 0; ct < 24; ++ct) {
        f32x4 acc = {0.f, 0.f, 0.f, 0.f};
        const unsigned short* bp = qkvW + (ct * 16 + m16) * 128 + g * 8;
        acc = mfma16(a0, *(const us8*)(bp),      acc);
        acc = mfma16(a1, *(const us8*)(bp + 32), acc);
        acc = mfma16(a2, *(const us8*)(bp + 64), acc);
        acc = mfma16(a3, *(const us8*)(bp + 96), acc);
        int c = ct * 16 + m16;
        float bias = qkvB[c];
        int s = ct >> 3;
        int rem = c & 127, hq = rem >> 5, hd = rem & 31;
        unsigned short* qdst = &sQ[wave][(s * 4 + hq) * 512 + hd];
        #pragma unroll
        for (int jj = 0; jj < 4; ++jj) {
            float v = acc[jj] + bias;
            if (s == 0) v *= SCALE_Q;
            qdst[(g * 4 + jj) * 32] = f2b(v);
        }
    }

    // ---- phase C: attention (lane = head*16 + query), all wave-local ----
    {
        const int h = g, n = m16;
        float qv[32];
        const unsigned short* qp = &sQ[wave][(h * 16 + n) * 32];
        #pragma unroll
        for (int d8 = 0; d8 < 4; ++d8) {
            us8 u = *(const us8*)(qp + d8 * 8);
            #pragma unroll
            for (int j = 0; j < 8; ++j) qv[d8 * 8 + j] = b2f(u[j]);
        }
        int ti = n >> 2, tj = n & 3;
        int hh2 = wh * 4 + ti, ww2 = wn * 4 + tj;
        int myid = (hh2 < 60 ? 0 : (hh2 < 62 ? 3 : 6)) + (ww2 < 60 ? 0 : (ww2 < 62 ? 1 : 2));
        float p[16];
        const unsigned short* kb = &sQ[wave][(4 + h) * 512];
        #pragma unroll
        for (int kp = 0; kp < 16; ++kp) {
            float acc = 0.f;
            const unsigned short* kr = kb + kp * 32;
            #pragma unroll
            for (int d8 = 0; d8 < 4; ++d8) {
                us8 u = *(const us8*)(kr + d8 * 8);
                #pragma unroll
                for (int j = 0; j < 8; ++j) acc += qv[d8 * 8 + j] * b2f(u[j]);
            }
            int pi = kp >> 2, pj = kp & 3;
            int ph = wh * 4 + pi, pw = wn * 4 + pj;
            int pid = (ph < 60 ? 0 : (ph < 62 ? 3 : 6)) + (pw < 60 ? 0 : (pw < 62 ? 1 : 2));
            acc += sbias[((ti - pi + 3) * 7 + (tj - pj + 3)) * 4 + h];
            if (pid != myid) acc -= 100.f;
            p[kp] = acc;
        }
        #pragma unroll
        for (int rep = 0; rep < 2; ++rep) {   // double softmax (faithful to reference)
            float mx = p[0];
            #pragma unroll
            for (int kp = 1; kp < 16; ++kp) mx = fmaxf(mx, p[kp]);
            float ssum = 0.f;
            #pragma unroll
            for (int kp = 0; kp < 16; ++kp) { p[kp] = __expf(p[kp] - mx); ssum += p[kp]; }
            float inv = 1.f / ssum;
            #pragma unroll
            for (int kp = 0; kp < 16; ++kp) p[kp] *= inv;
        }
        float o[32];
        #pragma unroll
        for (int d = 0; d < 32; ++d) o[d] = 0.f;
        const unsigned short* vb = &sQ[wave][(8 + h) * 512];
        #pragma unroll
        for (int kp = 0; kp < 16; ++kp) {
            const unsigned short* vr = vb + kp * 32;
            float w = p[kp];
            #pragma unroll
            for (int d8 = 0; d8 < 4; ++d8) {
                us8 u = *(const us8*)(vr + d8 * 8);
                #pragma unroll
                for (int j = 0; j < 8; ++j) o[d8 * 8 + j] += w * b2f(u[j]);
            }
        }
        // attn-out -> K region as [16][128] bf16, XOR-swizzled (proj A-tile)
        unsigned short* sO = &sQ[wave][2048];
        #pragma unroll
        for (int d8 = 0; d8 < 4; ++d8) {
            us8 u;
            #pragma unroll
            for (int j = 0; j < 8; ++j) u[j] = f2b(o[d8 * 8 + j]);
            lds_st8(sO, (n * 256) + (((h * 64 + d8 * 16)) ^ ((n & 7) << 4)), u);
        }
    }

    // ---- phase D: proj + window-reverse + roll + residual -> out ----
    {
        unsigned short* sO = &sQ[wave][2048];
        us8 c0 = lds_ld8(sO, (m16 * 256) + ((  0 + g * 16) ^ ((m16 & 7) << 4)));
        us8 c1 = lds_ld8(sO, (m16 * 256) + (( 64 + g * 16) ^ ((m16 & 7) << 4)));
        us8 c2 = lds_ld8(sO, (m16 * 256) + ((128 + g * 16) ^ ((m16 & 7) << 4)));
        us8 c3 = lds_ld8(sO, (m16 * 256) + ((192 + g * 16) ^ ((m16 & 7) << 4)));
        #pragma unroll
        for (int ct = 0; ct < 8; ++ct) {
            f32x4 acc = {0.f, 0.f, 0.f, 0.f};
            const unsigned short* bp = projW + (ct * 16 + m16) * 128 + g * 8;
            acc = mfma16(c0, *(const us8*)(bp),      acc);
            acc = mfma16(c1, *(const us8*)(bp + 32), acc);
            acc = mfma16(c2, *(const us8*)(bp + 64), acc);
            acc = mfma16(c3, *(const us8*)(bp + 96), acc);
            int c = ct * 16 + m16;
            float pb = projB[c];
            #pragma unroll
            for (int jj = 0; jj < 4; ++jj) {
                int tok = g * 4 + jj;
                int ti2 = tok >> 2, tj2 = tok & 3;
                int hh3 = (wh * 4 + ti2 + 2) & 63, ww3 = (wn * 4 + tj2 + 2) & 63;
                size_t t = (((size_t)bb << 12) | (hh3 << 6) | ww3);
                out[t * 128 + c] = acc[jj] + pb + x[t * 128 + c];
            }
        }
    }
}

// =====================================================================
// K2: LN2 + FC1 + GELU + FC2 + residual, in-place on out (64 rows/block)
// hH[64*512] bf16 (64KB); its first 16KB doubles as the LN'd A-tile.
// =====================================================================
__global__ __launch_bounds__(256) void k_block2(
    float* __restrict__ out,
    const float* __restrict__ ln2s, const float* __restrict__ ln2b,
    const unsigned short* __restrict__ fc1W, const float* __restrict__ fc1B,
    const unsigned short* __restrict__ fc2W, const float* __restrict__ fc2B)
{
    __shared__ unsigned short hH[64 * 512];
    const int tid = threadIdx.x;
    const int wave = tid >> 6, lane = tid & 63;
    const int g = lane >> 4, m16 = lane & 15;
    const size_t r0 = (size_t)blockIdx.x * 64;

    // ---- phase A: LN2 -> hA (= first 16KB of hH), [64][128] bf16 swizzled ----
    float4 sc0 = *(const float4*)(ln2s + m16 * 8);
    float4 sc1 = *(const float4*)(ln2s + m16 * 8 + 4);
    float4 bi0 = *(const float4*)(ln2b + m16 * 8);
    float4 bi1 = *(const float4*)(ln2b + m16 * 8 + 4);
    #pragma unroll
    for (int it = 0; it < 4; ++it) {
        int lr = wave * 16 + it * 4 + g;
        const float* xr = out + (r0 + lr) * 128 + m16 * 8;
        float4 v0 = *(const float4*)xr, v1 = *(const float4*)(xr + 4);
        float sum = v0.x + v0.y + v0.z + v0.w + v1.x + v1.y + v1.z + v1.w;
        float sq  = v0.x*v0.x + v0.y*v0.y + v0.z*v0.z + v0.w*v0.w
                  + v1.x*v1.x + v1.y*v1.y + v1.z*v1.z + v1.w*v1.w;
        #pragma unroll
        for (int m = 1; m < 16; m <<= 1) { sum += __shfl_xor(sum, m); sq += __shfl_xor(sq, m); }
        float mu = sum * 0.0078125f;
        float rstd = rsqrtf(sq * 0.0078125f - mu * mu + 1e-6f);
        us8 o;
        o[0] = f2b((v0.x - mu) * rstd * sc0.x + bi0.x);
        o[1] = f2b((v0.y - mu) * rstd * sc0.y + bi0.y);
        o[2] = f2b((v0.z - mu) * rstd * sc0.z + bi0.z);
        o[3] = f2b((v0.w - mu) * rstd * sc0.w + bi0.w);
        o[4] = f2b((v1.x - mu) * rstd * sc1.x + bi1.x);
        o[5] = f2b((v1.y - mu) * rstd * sc1.y + bi1.y);
        o[6] = f2b((v1.z - mu) * rstd * sc1.z + bi1.z);
        o[7] = f2b((v1.w - mu) * rstd * sc1.w + bi1.w);
        lds_st8(hH, (lr * 256) + ((m16 * 16) ^ ((lr & 7) << 4)), o);
    }
    __syncthreads();

    // hoist all A-frags (64 rows x K=128) to registers, then free hA for hidden
    us8 a[4][4];
    #pragma unroll
    for (int rf = 0; rf < 4; ++rf)
        #pragma unroll
        for (int kk = 0; kk < 4; ++kk)
            a[rf][kk] = lds_ld8(hH, ((rf * 16 + m16) * 256) + ((kk * 64 + g * 16) ^ ((m16 & 7) << 4)));
    __syncthreads();

    // ---- phase B: FC1 + GELU (wave owns cols wave*128..+128) -> hH [64][512] ----
    #pragma unroll
    for (int ct = 0; ct < 8; ++ct) {
        int c = wave * 128 + ct * 16 + m16;
        f32x4 acc[4] = {{0.f,0.f,0.f,0.f},{0.f,0.f,0.f,0.f},{0.f,0.f,0.f,0.f},{0.f,0.f,0.f,0.f}};
        const unsigned short* bp = fc1W + (size_t)c * 128 + g * 8;
        #pragma unroll
        for (int kk = 0; kk < 4; ++kk) {
            us8 b = *(const us8*)(bp + kk * 32);
            #pragma unroll
            for (int rf = 0; rf < 4; ++rf) acc[rf] = mfma16(a[rf][kk], b, acc[rf]);
        }
        float bias = fc1B[c];
        #pragma unroll
        for (int rf = 0; rf < 4; ++rf)
            #pragma unroll
            for (int jj = 0; jj < 4; ++jj) {
                float v = acc[rf][jj] + bias;
                float z = v + 0.044715f * v * v * v;
                float sg = 1.f / (1.f + __expf(-1.5957691216057308f * z));
                int row = rf * 16 + g * 4 + jj;
                *(unsigned short*)((char*)hH + (row * 1024 + ((c * 2) ^ ((row & 7) << 4)))) =
                    f2b(v * sg);
            }
    }
    __syncthreads();

    // ---- phase C: FC2 + residual (wave owns out cols wave*32..+32, K=512) ----
    #pragma unroll
    for (int ct = 0; ct < 2; ++ct) {
        int c = wave * 32 + ct * 16 + m16;
        f32x4 acc[4] = {{0.f,0.f,0.f,0.f},{0.f,0.f,0.f,0.f},{0.f,0.f,0.f,0.f},{0.f,0.f,0.f,0.f}};
        const unsigned short* bp = fc2W + (size_t)c * 512 + g * 8;
        #pragma unroll
        for (int kk = 0; kk < 16; ++kk) {
            us8 b = *(const us8*)(bp + kk * 32);
            #pragma unroll
            for (int rf = 0; rf < 4; ++rf) {
                us8 av = lds_ld8(hH, ((rf * 16 + m16) * 1024) + ((kk * 64 + g * 16) ^ ((m16 & 7) << 4)));
                acc[rf] = mfma16(av, b, acc[rf]);
            }
        }
        float bias = fc2B[c];
        #pragma unroll
        for (int rf = 0; rf < 4; ++rf)
            #pragma unroll
            for (int jj = 0; jj < 4; ++jj) {
                size_t row = r0 + rf * 16 + g * 4 + jj;
                float* op = out + row * 128 + c;
                *op = acc[rf][jj] + bias + *op;
            }
    }
}

// ---------- launch ----------
extern "C" void kernel_launch(void* const* d_in, const int* in_sizes, int n_in,
                              void* d_out, int out_size, void* d_ws, size_t ws_size,
                              hipStream_t stream) {
    const float* x        = (const float*)d_in[0];
    const float* ln1_s    = (const float*)d_in[1];
    const float* ln1_b    = (const float*)d_in[2];
    const float* qkv_w    = (const float*)d_in[3];
    const float* qkv_b    = (const float*)d_in[4];
    const float* rel_bias = (const float*)d_in[5];
    const float* proj_w   = (const float*)d_in[6];
    const float* proj_b   = (const float*)d_in[7];
    const float* ln2_s    = (const float*)d_in[8];
    const float* ln2_b    = (const float*)d_in[9];
    const float* fc1_w    = (const float*)d_in[10];
    const float* fc1_b    = (const float*)d_in[11];
    const float* fc2_w    = (const float*)d_in[12];
    const float* fc2_b    = (const float*)d_in[13];
    float* out = (float*)d_out;
    char* ws = (char*)d_ws;

    unsigned short* qkv_wt  = (unsigned short*)(ws);             // 384x128 bf16 (96KB)
    unsigned short* proj_wt = (unsigned short*)(ws + 98304);     // 128x128 (32KB)
    unsigned short* fc1_wt  = (unsigned short*)(ws + 131072);    // 512x128 (128KB)
    unsigned short* fc2_wt  = (unsigned short*)(ws + 262144);    // 128x512 (128KB)

    k_transpose<<<192, 256, 0, stream>>>(qkv_w, qkv_wt, 128, 384);
    k_transpose<<<64,  256, 0, stream>>>(proj_w, proj_wt, 128, 128);
    k_transpose<<<256, 256, 0, stream>>>(fc1_w, fc1_wt, 128, 512);
    k_transpose<<<256, 256, 0, stream>>>(fc2_w, fc2_wt, 512, 128);

    k_block1<<<4096, 256, 0, stream>>>(x, ln1_s, ln1_b, qkv_wt, qkv_b, rel_bias,
                                       proj_wt, proj_b, out);
    k_block2<<<4096, 256, 0, stream>>>(out, ln2_s, ln2_b, fc1_wt, fc1_b, fc2_wt, fc2_b);
}

// Round 3
// 299.773 us; speedup vs baseline: 3.8344x; 1.5216x over previous
//
#include <hip/hip_runtime.h>

typedef __bf16 bf16x8 __attribute__((ext_vector_type(8)));
typedef __bf16 bf16x4 __attribute__((ext_vector_type(4)));
typedef float f32x4 __attribute__((ext_vector_type(4)));
typedef unsigned short us8 __attribute__((ext_vector_type(8)));
typedef unsigned short us4 __attribute__((ext_vector_type(4)));
typedef short sh4 __attribute__((ext_vector_type(4)));

#define SCALE_Q 0.17677669529663687f  // 32^-0.5

__device__ __forceinline__ unsigned short f2b(float f) {
    union { float f; unsigned u; } v; v.f = f;
    unsigned r = v.u + 0x7FFFu + ((v.u >> 16) & 1u);   // RNE
    return (unsigned short)(r >> 16);
}
__device__ __forceinline__ float b2f(unsigned short h) {
    union { unsigned u; float f; } v; v.u = ((unsigned)h) << 16;
    return v.f;
}
__device__ __forceinline__ f32x4 mfma16(us8 a, us8 b, f32x4 c) {
    return __builtin_amdgcn_mfma_f32_16x16x32_bf16(
        __builtin_bit_cast(bf16x8, a), __builtin_bit_cast(bf16x8, b), c, 0, 0, 0);
}

// K=16 bf16 MFMA (PV step). A/B frag: 4 bf16, elem k=(lane>>4)*4+j.
#if __has_builtin(__builtin_amdgcn_mfma_f32_16x16x16bf16_1k)
#define PV_MFMA 1
__device__ __forceinline__ f32x4 mfma16k16(us4 a, us4 b, f32x4 c) {
    return __builtin_amdgcn_mfma_f32_16x16x16bf16_1k(
        __builtin_bit_cast(sh4, a), __builtin_bit_cast(sh4, b), c, 0, 0, 0);
}
#elif __has_builtin(__builtin_amdgcn_mfma_f32_16x16x16_bf16)
#define PV_MFMA 1
__device__ __forceinline__ f32x4 mfma16k16(us4 a, us4 b, f32x4 c) {
    return __builtin_amdgcn_mfma_f32_16x16x16_bf16(
        __builtin_bit_cast(bf16x4, a), __builtin_bit_cast(bf16x4, b), c, 0, 0, 0);
}
#endif

__device__ __forceinline__ us8 lds_ld8(const unsigned short* base, int byteoff) {
    return *(const us8*)((const char*)base + byteoff);
}
__device__ __forceinline__ void lds_st8(unsigned short* base, int byteoff, us8 v) {
    *(us8*)((char*)base + byteoff) = v;
}

// ---------- weight transpose + bf16 convert:  dst[c][r] = src[r][c] ----------
__global__ void k_transpose(const float* __restrict__ src, unsigned short* __restrict__ dst,
                            int R, int C) {
    int idx = blockIdx.x * 256 + threadIdx.x;
    if (idx >= R * C) return;
    int r = idx / C, c = idx - r * C;
    dst[c * R + r] = f2b(src[idx]);
}

// =====================================================================
// K1: LN1 + roll + window-partition + QKV + attention + proj + residual
// Block = 4 waves = 4 windows. Cooperative GEMMs (cols split by wave,
// B-frags reused across the 4 windows). Per-window 12 KB LDS:
//   [0..4096)   : Q [head][query][32d]   (aliases LN'd A-tile, then sO)
//   [4096..8192): K [head][key][32d]
//   [8192..12288): Vt [head][32d][16key]
// =====================================================================
__global__ __launch_bounds__(256, 3) void k_block1(
    const float* __restrict__ x,
    const float* __restrict__ ln1s, const float* __restrict__ ln1b,
    const unsigned short* __restrict__ qkvW, const float* __restrict__ qkvB,
    const float* __restrict__ relb,
    const unsigned short* __restrict__ projW, const float* __restrict__ projB,
    float* __restrict__ out)
{
    __shared__ unsigned short sm[4 * 6144];   // 48 KB
    __shared__ float sbias[196];
    const int tid = threadIdx.x;
    const int wave = tid >> 6, lane = tid & 63;
    const int g = lane >> 4, m16 = lane & 15;
    if (tid < 196) sbias[tid] = relb[tid];
    const int win0 = blockIdx.x * 4;
    const int winM = win0 + wave;
    const int bbM = winM >> 8, whM = (winM >> 4) & 15, wnM = winM & 15;

    // ---- phase A: LN1 + roll-gather -> A-tile [16][128] bf16, swizzled ----
    {
        float4 sc0 = *(const float4*)(ln1s + m16 * 8);
        float4 sc1 = *(const float4*)(ln1s + m16 * 8 + 4);
        float4 bi0 = *(const float4*)(ln1b + m16 * 8);
        float4 bi1 = *(const float4*)(ln1b + m16 * 8 + 4);
        #pragma unroll
        for (int it = 0; it < 4; ++it) {
            int tok = it * 4 + g;
            int ti = tok >> 2, tj = tok & 3;
            int hh = (whM * 4 + ti + 2) & 63, ww = (wnM * 4 + tj + 2) & 63;
            const float* xr = x + ((((size_t)bbM << 12) | (hh << 6) | ww) * 128) + m16 * 8;
            float4 v0 = *(const float4*)xr, v1 = *(const float4*)(xr + 4);
            float sum = v0.x + v0.y + v0.z + v0.w + v1.x + v1.y + v1.z + v1.w;
            float sq  = v0.x*v0.x + v0.y*v0.y + v0.z*v0.z + v0.w*v0.w
                      + v1.x*v1.x + v1.y*v1.y + v1.z*v1.z + v1.w*v1.w;
            #pragma unroll
            for (int m = 1; m < 16; m <<= 1) { sum += __shfl_xor(sum, m); sq += __shfl_xor(sq, m); }
            float mu = sum * 0.0078125f;
            float rstd = rsqrtf(sq * 0.0078125f - mu * mu + 1e-6f);
            us8 o;
            o[0] = f2b((v0.x - mu) * rstd * sc0.x + bi0.x);
            o[1] = f2b((v0.y - mu) * rstd * sc0.y + bi0.y);
            o[2] = f2b((v0.z - mu) * rstd * sc0.z + bi0.z);
            o[3] = f2b((v0.w - mu) * rstd * sc0.w + bi0.w);
            o[4] = f2b((v1.x - mu) * rstd * sc1.x + bi1.x);
            o[5] = f2b((v1.y - mu) * rstd * sc1.y + bi1.y);
            o[6] = f2b((v1.z - mu) * rstd * sc1.z + bi1.z);
            o[7] = f2b((v1.w - mu) * rstd * sc1.w + bi1.w);
            lds_st8(sm, wave * 12288 + tok * 256 + ((m16 * 16) ^ ((tok & 7) << 4)), o);
        }
    }
    __syncthreads();

    // ---- hoist A-frags of ALL 4 windows (Q region will be overwritten) ----
    us8 afr[4][4];
    #pragma unroll
    for (int w = 0; w < 4; ++w)
        #pragma unroll
        for (int k = 0; k < 4; ++k)
            afr[w][k] = lds_ld8(sm, w * 12288 + m16 * 256 + ((k * 64 + g * 16) ^ ((m16 & 7) << 4)));
    __syncthreads();

    // ---- phase B: QKV GEMM, cols split by wave (96 each), 4-window B-reuse ----
    #pragma unroll
    for (int ct = 0; ct < 6; ++ct) {
        const int cb = wave * 96 + ct * 16;
        const unsigned short* bp = qkvW + (cb + m16) * 128 + g * 8;
        us8 b0 = *(const us8*)(bp);
        us8 b1 = *(const us8*)(bp + 32);
        us8 b2 = *(const us8*)(bp + 64);
        us8 b3 = *(const us8*)(bp + 96);
        f32x4 acc[4] = {{0.f,0.f,0.f,0.f},{0.f,0.f,0.f,0.f},{0.f,0.f,0.f,0.f},{0.f,0.f,0.f,0.f}};
        #pragma unroll
        for (int w = 0; w < 4; ++w) {
            acc[w] = mfma16(afr[w][0], b0, acc[w]);
            acc[w] = mfma16(afr[w][1], b1, acc[w]);
            acc[w] = mfma16(afr[w][2], b2, acc[w]);
            acc[w] = mfma16(afr[w][3], b3, acc[w]);
        }
        const int c = cb + m16;
        const float bias = qkvB[c];
        const int s = c >> 7;                 // wave-uniform per ct
        const int rem = c & 127, hq = rem >> 5, hd = rem & 31;
        #pragma unroll
        for (int w = 0; w < 4; ++w) {
            const int base = w * 12288;
            if (s == 2) {                     // V: store transposed, packed b64
                us4 pk;
                #pragma unroll
                for (int jj = 0; jj < 4; ++jj) pk[jj] = f2b(acc[w][jj] + bias);
                *(us4*)((char*)sm + base + 8192 + hq * 1024 + hd * 32 + g * 8) = pk;
            } else {
                #pragma unroll
                for (int jj = 0; jj < 4; ++jj) {
                    float v = acc[w][jj] + bias;
                    if (s == 0) v *= SCALE_Q;
                    int tok = g * 4 + jj;
                    *(unsigned short*)((char*)sm + base + s * 4096 + hq * 1024 + tok * 64 + hd * 2)
                        = f2b(v);
                }
            }
        }
    }
    __syncthreads();

    // ---- phase C: attention via MFMA (wave-local window) ----
    {
        const int base = wave * 12288;
        const int ti = m16 >> 2, tj = m16 & 3;
        const int hhq = whM * 4 + ti, wwq = wnM * 4 + tj;
        const int myid = (hhq < 60 ? 0 : (hhq < 62 ? 3 : 6)) + (wwq < 60 ? 0 : (wwq < 62 ? 1 : 2));
        f32x4 po[4][2];
        #pragma unroll
        for (int h = 0; h < 4; ++h) {
            us8 kf = lds_ld8(sm, base + 4096 + h * 1024 + m16 * 64 + g * 16);
            us8 qf = lds_ld8(sm, base +        h * 1024 + m16 * 64 + g * 16);
            f32x4 st = mfma16(kf, qf, (f32x4){0.f,0.f,0.f,0.f});
            // st[jj] = S[query=m16][key=g*4+jj]
            float p[4];
            #pragma unroll
            for (int jj = 0; jj < 4; ++jj) {
                int kk = g * 4 + jj;
                int pi = kk >> 2, pj = kk & 3;
                int hhk = whM * 4 + pi, wwk = wnM * 4 + pj;
                int pid = (hhk < 60 ? 0 : (hhk < 62 ? 3 : 6)) + (wwk < 60 ? 0 : (wwk < 62 ? 1 : 2));
                float v = st[jj] + sbias[((ti - pi + 3) * 7 + (tj - pj + 3)) * 4 + h];
                p[jj] = (pid != myid) ? v - 100.f : v;
            }
            #pragma unroll
            for (int rep = 0; rep < 2; ++rep) {   // double softmax (faithful)
                float mx = fmaxf(fmaxf(p[0], p[1]), fmaxf(p[2], p[3]));
                mx = fmaxf(mx, __shfl_xor(mx, 16));
                mx = fmaxf(mx, __shfl_xor(mx, 32));
                float ssum = 0.f;
                #pragma unroll
                for (int jj = 0; jj < 4; ++jj) { p[jj] = __expf(p[jj] - mx); ssum += p[jj]; }
                ssum += __shfl_xor(ssum, 16);
                ssum += __shfl_xor(ssum, 32);
                float inv = 1.f / ssum;
                #pragma unroll
                for (int jj = 0; jj < 4; ++jj) p[jj] *= inv;
            }
#ifdef PV_MFMA
            us4 pf;
            #pragma unroll
            for (int jj = 0; jj < 4; ++jj) pf[jj] = f2b(p[jj]);
            #pragma unroll
            for (int dh = 0; dh < 2; ++dh) {
                us4 vf = *(const us4*)((const char*)sm + base + 8192 + h * 1024
                                       + (dh * 16 + m16) * 32 + g * 8);
                po[h][dh] = mfma16k16(vf, pf, (f32x4){0.f,0.f,0.f,0.f});
                // po[h][dh][jj] = out^T[d=dh*16+g*4+jj][q=m16]
            }
#else
            // fallback: gather all 16 probs via shfl, VALU PV
            unsigned u0 = ((unsigned)f2b(p[1]) << 16) | f2b(p[0]);
            unsigned u1 = ((unsigned)f2b(p[3]) << 16) | f2b(p[2]);
            unsigned a0 = __shfl_xor(u0, 16), a1 = __shfl_xor(u1, 16);
            unsigned b0_ = __shfl_xor(u0, 32), b1_ = __shfl_xor(u1, 32);
            unsigned c0_ = __shfl_xor(u0, 48), c1_ = __shfl_xor(u1, 48);
            #pragma unroll
            for (int dh = 0; dh < 2; ++dh) {
                f32x4 o4 = {0.f, 0.f, 0.f, 0.f};
                #pragma unroll
                for (int srcm = 0; srcm < 4; ++srcm) {
                    unsigned d0 = srcm == 0 ? u0 : srcm == 1 ? a0 : srcm == 2 ? b0_ : c0_;
                    unsigned d1 = srcm == 0 ? u1 : srcm == 1 ? a1 : srcm == 2 ? b1_ : c1_;
                    int kb = (g ^ srcm) * 4;
                    float pr[4] = { b2f((unsigned short)d0), b2f((unsigned short)(d0 >> 16)),
                                    b2f((unsigned short)d1), b2f((unsigned short)(d1 >> 16)) };
                    #pragma unroll
                    for (int jj = 0; jj < 4; ++jj) {
                        int d = dh * 16 + g * 4 + jj;
                        us4 vv = *(const us4*)((const char*)sm + base + 8192 + h * 1024
                                               + d * 32 + kb * 2);
                        #pragma unroll
                        for (int i = 0; i < 4; ++i) o4[jj] += pr[i] * b2f(vv[i]);
                    }
                }
                po[h][dh] = o4;
            }
#endif
        }
        // write sO (aliases Q region): [16 q][256B] swizzled; out[q][h*32+dh*16+g*4+jj]
        #pragma unroll
        for (int h = 0; h < 4; ++h)
            #pragma unroll
            for (int dh = 0; dh < 2; ++dh) {
                us4 pk;
                #pragma unroll
                for (int jj = 0; jj < 4; ++jj) pk[jj] = f2b(po[h][dh][jj]);
                *(us4*)((char*)sm + base + m16 * 256
                        + ((h * 64 + dh * 32 + g * 8) ^ ((m16 & 7) << 4))) = pk;
            }
    }
    __syncthreads();

    // ---- phase D: proj (cols split by wave: 32 each) + unroll-scatter + residual ----
    {
        us8 cfr[4][4];
        #pragma unroll
        for (int w = 0; w < 4; ++w)
            #pragma unroll
            for (int k = 0; k < 4; ++k)
                cfr[w][k] = lds_ld8(sm, w * 12288 + m16 * 256 + ((k * 64 + g * 16) ^ ((m16 & 7) << 4)));
        #pragma unroll
        for (int ct = 0; ct < 2; ++ct) {
            const int c = wave * 32 + ct * 16 + m16;
            const unsigned short* bp = projW + c * 128 + g * 8;
            us8 b0 = *(const us8*)(bp);
            us8 b1 = *(const us8*)(bp + 32);
            us8 b2 = *(const us8*)(bp + 64);
            us8 b3 = *(const us8*)(bp + 96);
            const float pb = projB[c];
            #pragma unroll
            for (int w = 0; w < 4; ++w) {
                f32x4 acc = {0.f, 0.f, 0.f, 0.f};
                acc = mfma16(cfr[w][0], b0, acc);
                acc = mfma16(cfr[w][1], b1, acc);
                acc = mfma16(cfr[w][2], b2, acc);
                acc = mfma16(cfr[w][3], b3, acc);
                const int winw = win0 + w;
                const int bb = winw >> 8, wh = (winw >> 4) & 15, wn = winw & 15;
                #pragma unroll
                for (int jj = 0; jj < 4; ++jj) {
                    int tok = g * 4 + jj;
                    int hh3 = (wh * 4 + (tok >> 2) + 2) & 63;
                    int ww3 = (wn * 4 + (tok & 3) + 2) & 63;
                    size_t t = (((size_t)bb << 12) | (hh3 << 6) | ww3);
                    out[t * 128 + c] = acc[jj] + pb + x[t * 128 + c];
                }
            }
        }
    }
}

// =====================================================================
// K2: LN2 + FC1 + GELU + FC2 + residual, in-place on out (64 rows/block)
// =====================================================================
__global__ __launch_bounds__(256) void k_block2(
    float* __restrict__ out,
    const float* __restrict__ ln2s, const float* __restrict__ ln2b,
    const unsigned short* __restrict__ fc1W, const float* __restrict__ fc1B,
    const unsigned short* __restrict__ fc2W, const float* __restrict__ fc2B)
{
    __shared__ unsigned short hH[64 * 512];
    const int tid = threadIdx.x;
    const int wave = tid >> 6, lane = tid & 63;
    const int g = lane >> 4, m16 = lane & 15;
    const size_t r0 = (size_t)blockIdx.x * 64;

    float4 sc0 = *(const float4*)(ln2s + m16 * 8);
    float4 sc1 = *(const float4*)(ln2s + m16 * 8 + 4);
    float4 bi0 = *(const float4*)(ln2b + m16 * 8);
    float4 bi1 = *(const float4*)(ln2b + m16 * 8 + 4);
    #pragma unroll
    for (int it = 0; it < 4; ++it) {
        int lr = wave * 16 + it * 4 + g;
        const float* xr = out + (r0 + lr) * 128 + m16 * 8;
        float4 v0 = *(const float4*)xr, v1 = *(const float4*)(xr + 4);
        float sum = v0.x + v0.y + v0.z + v0.w + v1.x + v1.y + v1.z + v1.w;
        float sq  = v0.x*v0.x + v0.y*v0.y + v0.z*v0.z + v0.w*v0.w
                  + v1.x*v1.x + v1.y*v1.y + v1.z*v1.z + v1.w*v1.w;
        #pragma unroll
        for (int m = 1; m < 16; m <<= 1) { sum += __shfl_xor(sum, m); sq += __shfl_xor(sq, m); }
        float mu = sum * 0.0078125f;
        float rstd = rsqrtf(sq * 0.0078125f - mu * mu + 1e-6f);
        us8 o;
        o[0] = f2b((v0.x - mu) * rstd * sc0.x + bi0.x);
        o[1] = f2b((v0.y - mu) * rstd * sc0.y + bi0.y);
        o[2] = f2b((v0.z - mu) * rstd * sc0.z + bi0.z);
        o[3] = f2b((v0.w - mu) * rstd * sc0.w + bi0.w);
        o[4] = f2b((v1.x - mu) * rstd * sc1.x + bi1.x);
        o[5] = f2b((v1.y - mu) * rstd * sc1.y + bi1.y);
        o[6] = f2b((v1.z - mu) * rstd * sc1.z + bi1.z);
        o[7] = f2b((v1.w - mu) * rstd * sc1.w + bi1.w);
        lds_st8(hH, (lr * 256) + ((m16 * 16) ^ ((lr & 7) << 4)), o);
    }
    __syncthreads();

    us8 a[4][4];
    #pragma unroll
    for (int rf = 0; rf < 4; ++rf)
        #pragma unroll
        for (int kk = 0; kk < 4; ++kk)
            a[rf][kk] = lds_ld8(hH, ((rf * 16 + m16) * 256) + ((kk * 64 + g * 16) ^ ((m16 & 7) << 4)));
    __syncthreads();

    #pragma unroll
    for (int ct = 0; ct < 8; ++ct) {
        int c = wave * 128 + ct * 16 + m16;
        f32x4 acc[4] = {{0.f,0.f,0.f,0.f},{0.f,0.f,0.f,0.f},{0.f,0.f,0.f,0.f},{0.f,0.f,0.f,0.f}};
        const unsigned short* bp = fc1W + (size_t)c * 128 + g * 8;
        #pragma unroll
        for (int kk = 0; kk < 4; ++kk) {
            us8 b = *(const us8*)(bp + kk * 32);
            #pragma unroll
            for (int rf = 0; rf < 4; ++rf) acc[rf] = mfma16(a[rf][kk], b, acc[rf]);
        }
        float bias = fc1B[c];
        #pragma unroll
        for (int rf = 0; rf < 4; ++rf)
            #pragma unroll
            for (int jj = 0; jj < 4; ++jj) {
                float v = acc[rf][jj] + bias;
                float z = v + 0.044715f * v * v * v;
                float sg = 1.f / (1.f + __expf(-1.5957691216057308f * z));
                int row = rf * 16 + g * 4 + jj;
                *(unsigned short*)((char*)hH + (row * 1024 + ((c * 2) ^ ((row & 7) << 4)))) =
                    f2b(v * sg);
            }
    }
    __syncthreads();

    #pragma unroll
    for (int ct = 0; ct < 2; ++ct) {
        int c = wave * 32 + ct * 16 + m16;
        f32x4 acc[4] = {{0.f,0.f,0.f,0.f},{0.f,0.f,0.f,0.f},{0.f,0.f,0.f,0.f},{0.f,0.f,0.f,0.f}};
        const unsigned short* bp = fc2W + (size_t)c * 512 + g * 8;
        #pragma unroll
        for (int kk = 0; kk < 16; ++kk) {
            us8 b = *(const us8*)(bp + kk * 32);
            #pragma unroll
            for (int rf = 0; rf < 4; ++rf) {
                us8 av = lds_ld8(hH, ((rf * 16 + m16) * 1024) + ((kk * 64 + g * 16) ^ ((m16 & 7) << 4)));
                acc[rf] = mfma16(av, b, acc[rf]);
            }
        }
        float bias = fc2B[c];
        #pragma unroll
        for (int rf = 0; rf < 4; ++rf)
            #pragma unroll
            for (int jj = 0; jj < 4; ++jj) {
                size_t row = r0 + rf * 16 + g * 4 + jj;
                float* op = out + row * 128 + c;
                *op = acc[rf][jj] + bias + *op;
            }
    }
}

// ---------- launch ----------
extern "C" void kernel_launch(void* const* d_in, const int* in_sizes, int n_in,
                              void* d_out, int out_size, void* d_ws, size_t ws_size,
                              hipStream_t stream) {
    const float* x        = (const float*)d_in[0];
    const float* ln1_s    = (const float*)d_in[1];
    const float* ln1_b    = (const float*)d_in[2];
    const float* qkv_w    = (const float*)d_in[3];
    const float* qkv_b    = (const float*)d_in[4];
    const float* rel_bias = (const float*)d_in[5];
    const float* proj_w   = (const float*)d_in[6];
    const float* proj_b   = (const float*)d_in[7];
    const float* ln2_s    = (const float*)d_in[8];
    const float* ln2_b    = (const float*)d_in[9];
    const float* fc1_w    = (const float*)d_in[10];
    const float* fc1_b    = (const float*)d_in[11];
    const float* fc2_w    = (const float*)d_in[12];
    const float* fc2_b    = (const float*)d_in[13];
    float* out = (float*)d_out;
    char* ws = (char*)d_ws;

    unsigned short* qkv_wt  = (unsigned short*)(ws);             // 384x128 bf16 (96KB)
    unsigned short* proj_wt = (unsigned short*)(ws + 98304);     // 128x128 (32KB)
    unsigned short* fc1_wt  = (unsigned short*)(ws + 131072);    // 512x128 (128KB)
    unsigned short* fc2_wt  = (unsigned short*)(ws + 262144);    // 128x512 (128KB)

    k_transpose<<<192, 256, 0, stream>>>(qkv_w, qkv_wt, 128, 384);
    k_transpose<<<64,  256, 0, stream>>>(proj_w, proj_wt, 128, 128);
    k_transpose<<<256, 256, 0, stream>>>(fc1_w, fc1_wt, 128, 512);
    k_transpose<<<256, 256, 0, stream>>>(fc2_w, fc2_wt, 512, 128);

    k_block1<<<4096, 256, 0, stream>>>(x, ln1_s, ln1_b, qkv_wt, qkv_b, rel_bias,
                                       proj_wt, proj_b, out);
    k_block2<<<4096, 256, 0, stream>>>(out, ln2_s, ln2_b, fc1_wt, fc1_b, fc2_wt, fc2_b);
}